// Round 11
// baseline (394.425 us; speedup 1.0000x reference)
//
#include <hip/hip_runtime.h>
#include <hip/hip_fp16.h>
#include <math.h>

#define WG 256

typedef _Float16 f16x8 __attribute__((ext_vector_type(8)));
typedef float    f32x4 __attribute__((ext_vector_type(4)));

// pair GELU: polynomial+clamp in f32, exp/ratio in packed f16. max |err| ~3e-3.
__device__ __forceinline__ __half2 gelu2(float xa, float xb) {
    float ua = 0.7978845608f * xa * fmaf(0.044715f * xa, xa, 1.0f);
    float ub = 0.7978845608f * xb * fmaf(0.044715f * xb, xb, 1.0f);
    ua = fminf(fmaxf(ua, -4.2f), 4.2f);
    ub = fminf(fmaxf(ub, -4.2f), 4.2f);
    const __half2 e   = h2exp(__float22half2_rn(make_float2(2.0f * ua, 2.0f * ub)));
    const __half2 one = __float2half2_rn(1.0f);
    const __half2 t   = __hmul2(__hsub2(e, one), h2rcp(__hadd2(e, one)));
    const float2  tf  = __half22float2(t);
    return __float22half2_rn(make_float2(0.5f * xa * (1.0f + tf.x),
                                         0.5f * xb * (1.0f + tf.y)));
}

// wave-private LDS fence: drain DS queue + compiler memory barrier
#define WAVE_LDS_FENCE() asm volatile("s_waitcnt lgkmcnt(0)" ::: "memory")

__device__ __forceinline__ void acc_h4(f32x4& s, uint2 r) {
    const __half2 ha = *(const __half2*)&r.x;
    const __half2 hb = *(const __half2*)&r.y;
    const float2 fa = __half22float2(ha);
    const float2 fb = __half22float2(hb);
    s[0] += fa.x; s[1] += fa.y; s[2] += fb.x; s[3] += fb.y;
}

// ---- K1: per-edge MLP via MFMA; slot-order ELL (es=64) ----
// Scatter floor is the 2 position atomics/edge (~23 G atomics/s device-wide,
// locality-insensitive — rounds 1/3/5/7/9/10). (WG,4) = round-7 proven
// best-behaved bounds (VGPR 64, no spill; (WG,6) spilled — round 8).
__global__ __launch_bounds__(WG, 4) void edge_mlp_mfma(
    const float* __restrict__ coords,
    const float* __restrict__ normals,
    const float* __restrict__ curv,
    const int*   __restrict__ eidx,
    const float* __restrict__ W1, const float* __restrict__ b1,
    const float* __restrict__ W2, const float* __restrict__ b2,
    const float* __restrict__ W3, const float* __restrict__ b3,
    int* __restrict__ cnt, _Float16* __restrict__ ellA,
    float* __restrict__ stats, int E)
{
    __shared__ __half h1s[4][32][68];   // layer-1 acts; reused as c3 transpose buf
    __shared__ __half h2s[4][32][36];   // layer-2 acts
    __shared__ float red[4][32];

    const int t    = threadIdx.x;
    const int w    = t >> 6;
    const int lane = t & 63;
    const int quad = lane >> 4;
    const int col  = lane & 15;

    // ---- per-lane edge ids + early atomics ----
    const int e  = blockIdx.x * WG + w * 64 + lane;
    const bool ev = (e < E);
    const int ec = ev ? e : 0;
    const int r = eidx[ec];
    const int c = eidx[E + ec];

    int pr = 0, qc = 0;
    if (ev) {
        pr = atomicAdd(&cnt[r], 1);
        qc = atomicAdd(&cnt[c], 1);
    }
    const int packR = (ev && pr < 64) ? (r * 64 + pr) : -1;
    const int packC = (ev && qc < 64) ? (c * 64 + qc) : -1;

    // ---- weight B-fragments in registers ----
    f16x8 bw1[4];
#pragma unroll
    for (int n = 0; n < 4; ++n) {
#pragma unroll
        for (int j = 0; j < 8; ++j) {
            const int k = quad * 8 + j;
            bw1[n][j] = (k < 8) ? (_Float16)W1[k * 64 + n * 16 + col] : (_Float16)0.f;
        }
    }
    f16x8 bw2[2][2];
#pragma unroll
    for (int s = 0; s < 2; ++s)
#pragma unroll
        for (int n = 0; n < 2; ++n)
#pragma unroll
            for (int j = 0; j < 8; ++j)
                bw2[s][n][j] = (_Float16)W2[(s * 32 + quad * 8 + j) * 32 + n * 16 + col];
    f16x8 bw3;
#pragma unroll
    for (int j = 0; j < 8; ++j)
        bw3[j] = (_Float16)W3[(quad * 8 + j) * 16 + col];

    float b1v[4], b2v[2], b3v;
#pragma unroll
    for (int n = 0; n < 4; ++n) b1v[n] = b1[n * 16 + col];
    b2v[0] = b2[col]; b2v[1] = b2[16 + col];
    b3v = b3[col];

    // ---- geometry -> f[8] ----
    const float rx = coords[3*r], ry = coords[3*r+1], rz = coords[3*r+2];
    const float cx = coords[3*c], cy = coords[3*c+1], cz = coords[3*c+2];
    const float dx = cx - rx, dy = cy - ry, dz = cz - rz;
    const float nrx = normals[3*r], nry = normals[3*r+1], nrz = normals[3*r+2];
    const float ncx = normals[3*c], ncy = normals[3*c+1], ncz = normals[3*c+2];

    const float ndot = nrx*ncx + nry*ncy + nrz*ncz;
    const float dn   = sqrtf(dx*dx + dy*dy + dz*dz) + 1e-8f;
    const float inv  = 1.0f / dn;
    const float lo = -1.0f + 1e-8f, hi = 1.0f - 1e-8f;
    const float cr = fminf(fmaxf((nrx*dx + nry*dy + nrz*dz) * inv, lo), hi);
    const float cc2 = fminf(fmaxf((ncx*dx + ncy*dy + ncz*dz) * inv, lo), hi);
    const float cd0 = curv[4*c]   - curv[4*r];
    const float cd1 = curv[4*c+1] - curv[4*r+1];

    float f[8] = {dx, dy, dz, ndot, cr, cc2, cd0, cd1};

    const int e0w = blockIdx.x * WG + w * 64;
    float vsum = 0.f, vsq = 0.f;

#pragma unroll
    for (int p = 0; p < 2; ++p) {
        // ======== phase 1: layer-1 for tiles mt=2p, 2p+1 ========
#pragma unroll
        for (int mtl = 0; mtl < 2; ++mtl) {
            const int mt = 2 * p + mtl;
            f16x8 a1;
#pragma unroll
            for (int j = 0; j < 8; ++j) {
                const float v = __shfl(f[j], (mt << 4) + col, 64);
                a1[j] = (quad == 0) ? (_Float16)v : (_Float16)0.f;
            }
            f32x4 c1[4];
#pragma unroll
            for (int n = 0; n < 4; ++n) {
                f32x4 c0 = {b1v[n], b1v[n], b1v[n], b1v[n]};
                c1[n] = __builtin_amdgcn_mfma_f32_16x16x32_f16(a1, bw1[n], c0, 0, 0, 0);
            }
#pragma unroll
            for (int np = 0; np < 2; ++np)
#pragma unroll
                for (int rg = 0; rg < 4; ++rg) {
                    const __half2 g = gelu2(c1[2*np][rg], c1[2*np+1][rg]);
                    __half* dst = &h1s[w][mtl*16 + quad*4 + rg][np*32 + col];
                    dst[0]  = __low2half(g);
                    dst[16] = __high2half(g);
                }
        }
        WAVE_LDS_FENCE();

        // ======== phase 2: layer-2 (both tiles, independent chains) ========
        f32x4 c2s[2][2];
#pragma unroll
        for (int mtl = 0; mtl < 2; ++mtl) {
            const f16x8 a2s0 = *(const f16x8*)&h1s[w][mtl*16 + col][quad * 8];
            const f16x8 a2s1 = *(const f16x8*)&h1s[w][mtl*16 + col][32 + quad * 8];
#pragma unroll
            for (int n = 0; n < 2; ++n) {
                f32x4 c0 = {b2v[n], b2v[n], b2v[n], b2v[n]};
                c0 = __builtin_amdgcn_mfma_f32_16x16x32_f16(a2s0, bw2[0][n], c0, 0, 0, 0);
                c2s[mtl][n] = __builtin_amdgcn_mfma_f32_16x16x32_f16(a2s1, bw2[1][n], c0, 0, 0, 0);
            }
        }
#pragma unroll
        for (int mtl = 0; mtl < 2; ++mtl)
#pragma unroll
            for (int rg = 0; rg < 4; ++rg) {
                const __half2 g = gelu2(c2s[mtl][0][rg], c2s[mtl][1][rg]);
                __half* dst = &h2s[w][mtl*16 + quad*4 + rg][col];
                dst[0]  = __low2half(g);
                dst[16] = __high2half(g);
            }
        WAVE_LDS_FENCE();

        // ======== phase 3: layer-3 + transpose + scatter ========
#pragma unroll
        for (int mtl = 0; mtl < 2; ++mtl) {
            const int mt = 2 * p + mtl;
            const f16x8 a3 = *(const f16x8*)&h2s[w][mtl*16 + col][quad * 8];
            f32x4 c0 = {b3v, b3v, b3v, b3v};
            const f32x4 c3 = __builtin_amdgcn_mfma_f32_16x16x32_f16(a3, bw3, c0, 0, 0, 0);

#pragma unroll
            for (int rg = 0; rg < 4; ++rg) {
                const int me = e0w + mt * 16 + quad * 4 + rg;
                if (me < E) { vsum += c3[rg]; vsq += c3[rg] * c3[rg]; }
            }
            // transpose staging into (dead) h1s region, cols 0..15
#pragma unroll
            for (int rg = 0; rg < 4; ++rg)
                h1s[w][mtl*16 + quad*4 + rg][col] = __float2half(c3[rg]);
        }

        WAVE_LDS_FENCE();
        {
            const int j    = lane >> 2;
            const int subl = lane & 3;
#pragma unroll
            for (int mtl = 0; mtl < 2; ++mtl) {
                const int mt = 2 * p + mtl;
                const uint2 v = *(const uint2*)&h1s[w][mtl*16 + j][subl * 4];
                const int srcl = (mt << 4) + j;
                const int dR = __shfl(packR, srcl, 64);
                const int dC = __shfl(packC, srcl, 64);
                if (dR >= 0) *(uint2*)((char*)ellA + (size_t)dR * 32 + subl * 8) = v;
                if (dC >= 0) *(uint2*)((char*)ellA + (size_t)dC * 32 + subl * 8) = v;
            }
        }
    }

    vsum += __shfl_xor(vsum, 16, 64);
    vsq  += __shfl_xor(vsq,  16, 64);
    vsum += __shfl_xor(vsum, 32, 64);
    vsq  += __shfl_xor(vsq,  32, 64);
    if (lane < 16) {
        red[w][col]      = vsum;
        red[w][16 + col] = vsq;
    }
    __syncthreads();
    if (t < 32) {
        const float s = red[0][t] + red[1][t] + red[2][t] + red[3][t];
        atomicAdd(&stats[t], s);
    }
}

// ---- gather: 8 lanes/node, 4 rows (128B) per iteration, unroll 2 ----
// Node block = 64 rows x 32B = 2048B. Lane h in [0,8): row sub = h>>1,
// channel half = h&1 (8 channels). 8 nodes/wave, 32 nodes/block.
__global__ __launch_bounds__(WG) void gather8_kernel(
    const _Float16* __restrict__ ellA, const int* __restrict__ cnt,
    const float* __restrict__ Wp, const float* __restrict__ bp,
    const float* __restrict__ gE, const float* __restrict__ bE,
    float* __restrict__ stats, float* __restrict__ X,
    int N, float invE)
{
    __shared__ float sWp[256];
    __shared__ float syv[4][8][17];   // padded: kills projection bank conflicts
    __shared__ float red2[4][32];

    const int t = threadIdx.x;
    sWp[t] = Wp[t];

    const int w    = t >> 6;
    const int lane = t & 63;
    const int g    = lane >> 3;        // node group 0..7
    const int h    = lane & 7;
    const int half = h & 1;
    const int rsub = h >> 1;           // row sub 0..3
    const int hb   = half * 8;         // channel base for gather

    // edge-BN coeffs for this lane's 8 channels
    float a8[8], b8[8];
#pragma unroll
    for (int cc = 0; cc < 8; ++cc) {
        const int ch = hb + cc;
        const float mean = stats[ch] * invE;
        const float var  = stats[16 + ch] * invE - mean * mean;
        a8[cc] = gE[ch] * rsqrtf(var + 1e-5f);
        b8[cc] = bE[ch] - mean * a8[cc];
    }

    const int node = blockIdx.x * 32 + w * 8 + g;

    f32x4 sA = {0.f,0.f,0.f,0.f}, sB = {0.f,0.f,0.f,0.f};
    int len = 0;
    if (node < N) {
        len = cnt[node];
        const int cap = len < 64 ? len : 64;
        const char* base = (const char*)ellA + (size_t)node * 2048
                         + rsub * 32 + half * 16;
        int i = 0;
#pragma unroll 2
        for (; i + 4 <= cap; i += 4) {
            const uint4 rr = *(const uint4*)(base + (size_t)i * 32);
            acc_h4(sA, make_uint2(rr.x, rr.y));
            acc_h4(sB, make_uint2(rr.z, rr.w));
        }
        if (i < cap && rsub < (cap - i)) {
            const uint4 rr = *(const uint4*)(base + (size_t)i * 32);
            acc_h4(sA, make_uint2(rr.x, rr.y));
            acc_h4(sB, make_uint2(rr.z, rr.w));
        }
    }
    // reduce across the 4 row-subs (lanes differing in h bits 1,2)
#pragma unroll
    for (int cc = 0; cc < 4; ++cc) {
        sA[cc] += __shfl_xor(sA[cc], 2, 64);
        sB[cc] += __shfl_xor(sB[cc], 2, 64);
        sA[cc] += __shfl_xor(sA[cc], 4, 64);
        sB[cc] += __shfl_xor(sB[cc], 4, 64);
    }

    const float d    = (float)len;
    const float invd = 1.0f / fmaxf(d, 1.0f);
    if (rsub == 0) {   // lanes h=0 (ch 0-7) and h=1 (ch 8-15)
#pragma unroll
        for (int cc = 0; cc < 4; ++cc) {
            syv[w][g][hb + cc]     = (a8[cc]     * sA[cc] + b8[cc]     * d) * invd;
            syv[w][g][hb + 4 + cc] = (a8[4 + cc] * sB[cc] + b8[4 + cc] * d) * invd;
        }
    }
    __syncthreads();   // covers sWp + syv

    // projection: 2 output channels per lane
    const int c2 = 2 * h;
    float x0 = bp[c2], x1 = bp[c2 + 1];
#pragma unroll
    for (int j = 0; j < 16; ++j) {
        const float yj = syv[w][g][j];
        x0 += yj * sWp[j * 16 + c2];
        x1 += yj * sWp[j * 16 + c2 + 1];
    }

    if (node < N) {
        *(float2*)&X[(size_t)node * 16 + c2] = make_float2(x0, x1);
    } else {
        x0 = 0.f; x1 = 0.f;
    }

    // node-BN stats
    float vs0 = x0, vs1 = x1, vq0 = x0 * x0, vq1 = x1 * x1;
#pragma unroll
    for (int off = 8; off <= 32; off <<= 1) {
        vs0 += __shfl_xor(vs0, off, 64);
        vs1 += __shfl_xor(vs1, off, 64);
        vq0 += __shfl_xor(vq0, off, 64);
        vq1 += __shfl_xor(vq1, off, 64);
    }
    if (lane < 8) {
        red2[w][c2]          = vs0;
        red2[w][c2 + 1]      = vs1;
        red2[w][16 + c2]     = vq0;
        red2[w][16 + c2 + 1] = vq1;
    }
    __syncthreads();
    if (t < 32) {
        const float ssum = red2[0][t] + red2[1][t] + red2[2][t] + red2[3][t];
        atomicAdd(&stats[32 + t], ssum);
    }
}

// ---- apply node BN (in-place, X == out) ----
__global__ __launch_bounds__(WG) void out_kernel(
    const float* __restrict__ X, const float* __restrict__ stats,
    const float* __restrict__ gN, const float* __restrict__ bN,
    float* __restrict__ out, int total, float invN)
{
    __shared__ float sA[16], sB[16];
    if (threadIdx.x < 16) {
        const int k = threadIdx.x;
        const float mean = stats[32 + k] * invN;
        const float var  = stats[48 + k] * invN - mean * mean;
        const float a    = gN[k] / sqrtf(var + 1e-5f);
        sA[k] = a;
        sB[k] = bN[k] - mean * a;
    }
    __syncthreads();
    const int i = blockIdx.x * WG + threadIdx.x;
    if (i < total) {
        out[i] = sA[i & 15] * X[i] + sB[i & 15];
    }
}

// ============================ LAUNCH ============================

extern "C" void kernel_launch(void* const* d_in, const int* in_sizes, int n_in,
                              void* d_out, int out_size, void* d_ws, size_t ws_size,
                              hipStream_t stream)
{
    const float* coords  = (const float*)d_in[0];
    const float* normals = (const float*)d_in[1];
    const float* curv    = (const float*)d_in[2];
    const int*   eidx    = (const int*)d_in[3];
    const float* W1 = (const float*)d_in[4];
    const float* b1 = (const float*)d_in[5];
    const float* W2 = (const float*)d_in[6];
    const float* b2 = (const float*)d_in[7];
    const float* W3 = (const float*)d_in[8];
    const float* b3 = (const float*)d_in[9];
    const float* gE = (const float*)d_in[10];
    const float* bE = (const float*)d_in[11];
    const float* Wp = (const float*)d_in[12];
    const float* bp = (const float*)d_in[13];
    const float* gN = (const float*)d_in[14];
    const float* bN = (const float*)d_in[15];

    const int N = in_sizes[0] / 3;
    const int E = in_sizes[3] / 2;
    const int eblk = (E + WG - 1) / WG;
    float* out = (float*)d_out;

    // ws layout (es=64): stats[64] | cnt[N] | ellA[N*64 rows x 32B] ~ 206 MB
    // (proven to fit: rounds 4-10 all ran this path)
    const size_t off_cnt   = 256;
    const size_t cnt_bytes = (((size_t)N * 4) + 255) & ~(size_t)255;

    float*    stats = (float*)d_ws;
    int*      cnt   = (int*)((char*)d_ws + off_cnt);
    _Float16* ellA  = (_Float16*)((char*)d_ws + off_cnt + cnt_bytes);

    hipMemsetAsync(d_ws, 0, off_cnt + (size_t)N * 4, stream);

    edge_mlp_mfma<<<dim3(eblk), dim3(WG), 0, stream>>>(
        coords, normals, curv, eidx, W1, b1, W2, b2, W3, b3,
        cnt, ellA, stats, E);

    gather8_kernel<<<dim3((N + 31) / 32), dim3(WG), 0, stream>>>(
        ellA, cnt, Wp, bp, gE, bE, stats, out, N, 1.0f / (float)E);

    out_kernel<<<dim3((N * 16 + WG - 1) / WG), dim3(WG), 0, stream>>>(
        out, stats, gN, bN, out, N * 16, 1.0f / (float)N);
}

// Round 12
// 372.239 us; speedup vs baseline: 1.0596x; 1.0596x over previous
//
#include <hip/hip_runtime.h>
#include <hip/hip_fp16.h>
#include <math.h>

#define WG 256

typedef _Float16 f16x8 __attribute__((ext_vector_type(8)));
typedef float    f32x4 __attribute__((ext_vector_type(4)));

// pair GELU: polynomial+clamp in f32, exp/ratio in packed f16. max |err| ~3e-3.
__device__ __forceinline__ __half2 gelu2(float xa, float xb) {
    float ua = 0.7978845608f * xa * fmaf(0.044715f * xa, xa, 1.0f);
    float ub = 0.7978845608f * xb * fmaf(0.044715f * xb, xb, 1.0f);
    ua = fminf(fmaxf(ua, -4.2f), 4.2f);
    ub = fminf(fmaxf(ub, -4.2f), 4.2f);
    const __half2 e   = h2exp(__float22half2_rn(make_float2(2.0f * ua, 2.0f * ub)));
    const __half2 one = __float2half2_rn(1.0f);
    const __half2 t   = __hmul2(__hsub2(e, one), h2rcp(__hadd2(e, one)));
    const float2  tf  = __half22float2(t);
    return __float22half2_rn(make_float2(0.5f * xa * (1.0f + tf.x),
                                         0.5f * xb * (1.0f + tf.y)));
}

#define WAVE_LDS_FENCE() asm volatile("s_waitcnt lgkmcnt(0)" ::: "memory")

__device__ __forceinline__ void acc_h4(f32x4& s, uint2 r) {
    const __half2 ha = *(const __half2*)&r.x;
    const __half2 hb = *(const __half2*)&r.y;
    const float2 fa = __half22float2(ha);
    const float2 fb = __half22float2(hb);
    s[0] += fa.x; s[1] += fa.y; s[2] += fb.x; s[3] += fb.y;
}

// ================= f32 full-line path =================

// ---- K1: per-edge MLP via MFMA; slot-order ELL, 64B line-aligned f32 rows ----
// Full-line coalesced stores (4 lanes x dwordx4 = one 64B line) eliminate the
// read-for-ownership fetch that round-11 counters showed (FETCH ~= 1 line/store).
__global__ __launch_bounds__(WG, 4) void edge_mlp_f32(
    const float* __restrict__ coords,
    const float* __restrict__ normals,
    const float* __restrict__ curv,
    const int*   __restrict__ eidx,
    const float* __restrict__ W1, const float* __restrict__ b1,
    const float* __restrict__ W2, const float* __restrict__ b2,
    const float* __restrict__ W3, const float* __restrict__ b3,
    int* __restrict__ cnt, float* __restrict__ ellA,
    float* __restrict__ stats, int E)
{
    __shared__ __half h1s[4][32][68];
    __shared__ __half h2s[4][32][36];
    __shared__ float  tr[4][32][20];   // f32 transpose buf; stride 20 -> 16B-aligned rows
    __shared__ float  red[4][32];

    const int t    = threadIdx.x;
    const int w    = t >> 6;
    const int lane = t & 63;
    const int quad = lane >> 4;
    const int col  = lane & 15;

    const int e  = blockIdx.x * WG + w * 64 + lane;
    const bool ev = (e < E);
    const int ec = ev ? e : 0;
    const int r = eidx[ec];
    const int c = eidx[E + ec];

    int pr = 0, qc = 0;
    if (ev) {
        pr = atomicAdd(&cnt[r], 1);
        qc = atomicAdd(&cnt[c], 1);
    }
    const int packR = (ev && pr < 64) ? (r * 64 + pr) : -1;
    const int packC = (ev && qc < 64) ? (c * 64 + qc) : -1;

    f16x8 bw1[4];
#pragma unroll
    for (int n = 0; n < 4; ++n) {
#pragma unroll
        for (int j = 0; j < 8; ++j) {
            const int k = quad * 8 + j;
            bw1[n][j] = (k < 8) ? (_Float16)W1[k * 64 + n * 16 + col] : (_Float16)0.f;
        }
    }
    f16x8 bw2[2][2];
#pragma unroll
    for (int s = 0; s < 2; ++s)
#pragma unroll
        for (int n = 0; n < 2; ++n)
#pragma unroll
            for (int j = 0; j < 8; ++j)
                bw2[s][n][j] = (_Float16)W2[(s * 32 + quad * 8 + j) * 32 + n * 16 + col];
    f16x8 bw3;
#pragma unroll
    for (int j = 0; j < 8; ++j)
        bw3[j] = (_Float16)W3[(quad * 8 + j) * 16 + col];

    float b1v[4], b2v[2], b3v;
#pragma unroll
    for (int n = 0; n < 4; ++n) b1v[n] = b1[n * 16 + col];
    b2v[0] = b2[col]; b2v[1] = b2[16 + col];
    b3v = b3[col];

    const float rx = coords[3*r], ry = coords[3*r+1], rz = coords[3*r+2];
    const float cx = coords[3*c], cy = coords[3*c+1], cz = coords[3*c+2];
    const float dx = cx - rx, dy = cy - ry, dz = cz - rz;
    const float nrx = normals[3*r], nry = normals[3*r+1], nrz = normals[3*r+2];
    const float ncx = normals[3*c], ncy = normals[3*c+1], ncz = normals[3*c+2];

    const float ndot = nrx*ncx + nry*ncy + nrz*ncz;
    const float dn   = sqrtf(dx*dx + dy*dy + dz*dz) + 1e-8f;
    const float inv  = 1.0f / dn;
    const float lo = -1.0f + 1e-8f, hi = 1.0f - 1e-8f;
    const float cr = fminf(fmaxf((nrx*dx + nry*dy + nrz*dz) * inv, lo), hi);
    const float cc2 = fminf(fmaxf((ncx*dx + ncy*dy + ncz*dz) * inv, lo), hi);
    const float cd0 = curv[4*c]   - curv[4*r];
    const float cd1 = curv[4*c+1] - curv[4*r+1];

    float f[8] = {dx, dy, dz, ndot, cr, cc2, cd0, cd1};

    const int e0w = blockIdx.x * WG + w * 64;
    float vsum = 0.f, vsq = 0.f;

#pragma unroll
    for (int p = 0; p < 2; ++p) {
        // ---- phase 1: layer-1 for tiles 2p, 2p+1 ----
#pragma unroll
        for (int mtl = 0; mtl < 2; ++mtl) {
            const int mt = 2 * p + mtl;
            f16x8 a1;
#pragma unroll
            for (int j = 0; j < 8; ++j) {
                const float v = __shfl(f[j], (mt << 4) + col, 64);
                a1[j] = (quad == 0) ? (_Float16)v : (_Float16)0.f;
            }
            f32x4 c1[4];
#pragma unroll
            for (int n = 0; n < 4; ++n) {
                f32x4 c0 = {b1v[n], b1v[n], b1v[n], b1v[n]};
                c1[n] = __builtin_amdgcn_mfma_f32_16x16x32_f16(a1, bw1[n], c0, 0, 0, 0);
            }
#pragma unroll
            for (int np = 0; np < 2; ++np)
#pragma unroll
                for (int rg = 0; rg < 4; ++rg) {
                    const __half2 g = gelu2(c1[2*np][rg], c1[2*np+1][rg]);
                    __half* dst = &h1s[w][mtl*16 + quad*4 + rg][np*32 + col];
                    dst[0]  = __low2half(g);
                    dst[16] = __high2half(g);
                }
        }
        WAVE_LDS_FENCE();

        // ---- phase 2: layer-2 ----
        f32x4 c2s[2][2];
#pragma unroll
        for (int mtl = 0; mtl < 2; ++mtl) {
            const f16x8 a2s0 = *(const f16x8*)&h1s[w][mtl*16 + col][quad * 8];
            const f16x8 a2s1 = *(const f16x8*)&h1s[w][mtl*16 + col][32 + quad * 8];
#pragma unroll
            for (int n = 0; n < 2; ++n) {
                f32x4 c0 = {b2v[n], b2v[n], b2v[n], b2v[n]};
                c0 = __builtin_amdgcn_mfma_f32_16x16x32_f16(a2s0, bw2[0][n], c0, 0, 0, 0);
                c2s[mtl][n] = __builtin_amdgcn_mfma_f32_16x16x32_f16(a2s1, bw2[1][n], c0, 0, 0, 0);
            }
        }
#pragma unroll
        for (int mtl = 0; mtl < 2; ++mtl)
#pragma unroll
            for (int rg = 0; rg < 4; ++rg) {
                const __half2 g = gelu2(c2s[mtl][0][rg], c2s[mtl][1][rg]);
                __half* dst = &h2s[w][mtl*16 + quad*4 + rg][col];
                dst[0]  = __low2half(g);
                dst[16] = __high2half(g);
            }
        WAVE_LDS_FENCE();

        // ---- phase 3: layer-3 + f32 transpose ----
#pragma unroll
        for (int mtl = 0; mtl < 2; ++mtl) {
            const int mt = 2 * p + mtl;
            const f16x8 a3 = *(const f16x8*)&h2s[w][mtl*16 + col][quad * 8];
            f32x4 c0 = {b3v, b3v, b3v, b3v};
            const f32x4 c3 = __builtin_amdgcn_mfma_f32_16x16x32_f16(a3, bw3, c0, 0, 0, 0);

#pragma unroll
            for (int rg = 0; rg < 4; ++rg) {
                const int me = e0w + mt * 16 + quad * 4 + rg;
                if (me < E) { vsum += c3[rg]; vsq += c3[rg] * c3[rg]; }
            }
#pragma unroll
            for (int rg = 0; rg < 4; ++rg)
                tr[w][mtl*16 + quad*4 + rg][col] = c3[rg];
        }

        WAVE_LDS_FENCE();
        // ---- full-line scatter: 4-lane group owns one 64B row ----
        {
            const int j    = lane >> 2;
            const int subl = lane & 3;
#pragma unroll
            for (int mtl = 0; mtl < 2; ++mtl) {
                const int mt = 2 * p + mtl;
                const uint4 v = *(const uint4*)&tr[w][mtl*16 + j][subl * 4];
                const int srcl = (mt << 4) + j;
                const int dR = __shfl(packR, srcl, 64);
                const int dC = __shfl(packC, srcl, 64);
                if (dR >= 0) *(uint4*)((char*)ellA + (size_t)dR * 64 + subl * 16) = v;
                if (dC >= 0) *(uint4*)((char*)ellA + (size_t)dC * 64 + subl * 16) = v;
            }
        }
    }

    vsum += __shfl_xor(vsum, 16, 64);
    vsq  += __shfl_xor(vsq,  16, 64);
    vsum += __shfl_xor(vsum, 32, 64);
    vsq  += __shfl_xor(vsq,  32, 64);
    if (lane < 16) {
        red[w][col]      = vsum;
        red[w][16 + col] = vsq;
    }
    __syncthreads();
    if (t < 32) {
        const float s = red[0][t] + red[1][t] + red[2][t] + red[3][t];
        atomicAdd(&stats[t], s);
    }
}

// ---- gather (f32 rows): 4 lanes/node, 1 row (64B) per iter, unroll 4 ----
__global__ __launch_bounds__(WG) void gather_f32(
    const float* __restrict__ ellA, const int* __restrict__ cnt,
    const float* __restrict__ Wp, const float* __restrict__ bp,
    const float* __restrict__ gE, const float* __restrict__ bE,
    float* __restrict__ stats, float* __restrict__ X,
    int N, float invE)
{
    __shared__ float sWp[256];
    __shared__ f32x4 syv[4][16][4];
    __shared__ float red2[4][32];

    const int t = threadIdx.x;
    sWp[t] = Wp[t];

    const int w    = t >> 6;
    const int lane = t & 63;
    const int g    = lane >> 2;
    const int subl = lane & 3;
    const int c0   = subl * 4;

    float a[4], bb[4], bpv[4];
#pragma unroll
    for (int cc = 0; cc < 4; ++cc) {
        const int ch = c0 + cc;
        const float mean = stats[ch] * invE;
        const float var  = stats[16 + ch] * invE - mean * mean;
        a[cc]  = gE[ch] * rsqrtf(var + 1e-5f);
        bb[cc] = bE[ch] - mean * a[cc];
        bpv[cc] = bp[ch];
    }

    const int node = blockIdx.x * 64 + w * 16 + g;

    f32x4 s = {0.f, 0.f, 0.f, 0.f};
    int len = 0;
    if (node < N) {
        len = cnt[node];
        const int cap = len < 64 ? len : 64;
        const char* base = (const char*)ellA + (size_t)node * 4096 + subl * 16;
        int i = 0;
        for (; i + 4 <= cap; i += 4) {
            const f32x4 r0 = *(const f32x4*)(base + (size_t)(i    ) * 64);
            const f32x4 r1 = *(const f32x4*)(base + (size_t)(i + 1) * 64);
            const f32x4 r2 = *(const f32x4*)(base + (size_t)(i + 2) * 64);
            const f32x4 r3 = *(const f32x4*)(base + (size_t)(i + 3) * 64);
            s += r0; s += r1; s += r2; s += r3;
        }
        for (; i < cap; ++i)
            s += *(const f32x4*)(base + (size_t)i * 64);
    }

    const float d    = (float)len;
    const float invd = 1.0f / fmaxf(d, 1.0f);
    f32x4 y;
#pragma unroll
    for (int cc = 0; cc < 4; ++cc)
        y[cc] = (a[cc] * s[cc] + bb[cc] * d) * invd;

    syv[w][g][subl] = y;
    __syncthreads();

    const f32x4 y0 = syv[w][g][0];
    const f32x4 y1 = syv[w][g][1];
    const f32x4 y2 = syv[w][g][2];
    const f32x4 y3 = syv[w][g][3];

    const f32x4* sWp4 = (const f32x4*)sWp;
    f32x4 x = {bpv[0], bpv[1], bpv[2], bpv[3]};
#pragma unroll
    for (int j = 0; j < 4; ++j) {
        const f32x4 wj = sWp4[j * 4 + subl];
#pragma unroll
        for (int cc = 0; cc < 4; ++cc) x[cc] += y0[j] * wj[cc];
    }
#pragma unroll
    for (int j = 0; j < 4; ++j) {
        const f32x4 wj = sWp4[(4 + j) * 4 + subl];
#pragma unroll
        for (int cc = 0; cc < 4; ++cc) x[cc] += y1[j] * wj[cc];
    }
#pragma unroll
    for (int j = 0; j < 4; ++j) {
        const f32x4 wj = sWp4[(8 + j) * 4 + subl];
#pragma unroll
        for (int cc = 0; cc < 4; ++cc) x[cc] += y2[j] * wj[cc];
    }
#pragma unroll
    for (int j = 0; j < 4; ++j) {
        const f32x4 wj = sWp4[(12 + j) * 4 + subl];
#pragma unroll
        for (int cc = 0; cc < 4; ++cc) x[cc] += y3[j] * wj[cc];
    }

    if (node < N) {
        *(f32x4*)&X[(size_t)node * 16 + c0] = x;
    } else {
        x = (f32x4){0.f, 0.f, 0.f, 0.f};
    }

    f32x4 vs = x, vq;
#pragma unroll
    for (int cc = 0; cc < 4; ++cc) vq[cc] = x[cc] * x[cc];
#pragma unroll
    for (int off = 4; off <= 32; off <<= 1) {
#pragma unroll
        for (int cc = 0; cc < 4; ++cc) {
            vs[cc] += __shfl_xor(vs[cc], off, 64);
            vq[cc] += __shfl_xor(vq[cc], off, 64);
        }
    }
    if (lane < 4) {
#pragma unroll
        for (int cc = 0; cc < 4; ++cc) {
            red2[w][c0 + cc]      = vs[cc];
            red2[w][16 + c0 + cc] = vq[cc];
        }
    }
    __syncthreads();
    if (t < 32) {
        const float ssum = red2[0][t] + red2[1][t] + red2[2][t] + red2[3][t];
        atomicAdd(&stats[32 + t], ssum);
    }
}

// ================= f16 fallback path (round-7/11 proven) =================

__global__ __launch_bounds__(WG, 4) void edge_mlp_f16(
    const float* __restrict__ coords,
    const float* __restrict__ normals,
    const float* __restrict__ curv,
    const int*   __restrict__ eidx,
    const float* __restrict__ W1, const float* __restrict__ b1,
    const float* __restrict__ W2, const float* __restrict__ b2,
    const float* __restrict__ W3, const float* __restrict__ b3,
    int* __restrict__ cnt, _Float16* __restrict__ ellA,
    float* __restrict__ stats, int E)
{
    __shared__ __half h1s[4][32][68];
    __shared__ __half h2s[4][32][36];
    __shared__ float red[4][32];

    const int t    = threadIdx.x;
    const int w    = t >> 6;
    const int lane = t & 63;
    const int quad = lane >> 4;
    const int col  = lane & 15;

    const int e  = blockIdx.x * WG + w * 64 + lane;
    const bool ev = (e < E);
    const int ec = ev ? e : 0;
    const int r = eidx[ec];
    const int c = eidx[E + ec];

    int pr = 0, qc = 0;
    if (ev) {
        pr = atomicAdd(&cnt[r], 1);
        qc = atomicAdd(&cnt[c], 1);
    }
    const int packR = (ev && pr < 64) ? (r * 64 + pr) : -1;
    const int packC = (ev && qc < 64) ? (c * 64 + qc) : -1;

    f16x8 bw1[4];
#pragma unroll
    for (int n = 0; n < 4; ++n) {
#pragma unroll
        for (int j = 0; j < 8; ++j) {
            const int k = quad * 8 + j;
            bw1[n][j] = (k < 8) ? (_Float16)W1[k * 64 + n * 16 + col] : (_Float16)0.f;
        }
    }
    f16x8 bw2[2][2];
#pragma unroll
    for (int s = 0; s < 2; ++s)
#pragma unroll
        for (int n = 0; n < 2; ++n)
#pragma unroll
            for (int j = 0; j < 8; ++j)
                bw2[s][n][j] = (_Float16)W2[(s * 32 + quad * 8 + j) * 32 + n * 16 + col];
    f16x8 bw3;
#pragma unroll
    for (int j = 0; j < 8; ++j)
        bw3[j] = (_Float16)W3[(quad * 8 + j) * 16 + col];

    float b1v[4], b2v[2], b3v;
#pragma unroll
    for (int n = 0; n < 4; ++n) b1v[n] = b1[n * 16 + col];
    b2v[0] = b2[col]; b2v[1] = b2[16 + col];
    b3v = b3[col];

    const float rx = coords[3*r], ry = coords[3*r+1], rz = coords[3*r+2];
    const float cx = coords[3*c], cy = coords[3*c+1], cz = coords[3*c+2];
    const float dx = cx - rx, dy = cy - ry, dz = cz - rz;
    const float nrx = normals[3*r], nry = normals[3*r+1], nrz = normals[3*r+2];
    const float ncx = normals[3*c], ncy = normals[3*c+1], ncz = normals[3*c+2];

    const float ndot = nrx*ncx + nry*ncy + nrz*ncz;
    const float dn   = sqrtf(dx*dx + dy*dy + dz*dz) + 1e-8f;
    const float inv  = 1.0f / dn;
    const float lo = -1.0f + 1e-8f, hi = 1.0f - 1e-8f;
    const float cr = fminf(fmaxf((nrx*dx + nry*dy + nrz*dz) * inv, lo), hi);
    const float cc2 = fminf(fmaxf((ncx*dx + ncy*dy + ncz*dz) * inv, lo), hi);
    const float cd0 = curv[4*c]   - curv[4*r];
    const float cd1 = curv[4*c+1] - curv[4*r+1];

    float f[8] = {dx, dy, dz, ndot, cr, cc2, cd0, cd1};

    const int e0w = blockIdx.x * WG + w * 64;
    float vsum = 0.f, vsq = 0.f;

#pragma unroll
    for (int p = 0; p < 2; ++p) {
#pragma unroll
        for (int mtl = 0; mtl < 2; ++mtl) {
            const int mt = 2 * p + mtl;
            f16x8 a1;
#pragma unroll
            for (int j = 0; j < 8; ++j) {
                const float v = __shfl(f[j], (mt << 4) + col, 64);
                a1[j] = (quad == 0) ? (_Float16)v : (_Float16)0.f;
            }
            f32x4 c1[4];
#pragma unroll
            for (int n = 0; n < 4; ++n) {
                f32x4 c0 = {b1v[n], b1v[n], b1v[n], b1v[n]};
                c1[n] = __builtin_amdgcn_mfma_f32_16x16x32_f16(a1, bw1[n], c0, 0, 0, 0);
            }
#pragma unroll
            for (int np = 0; np < 2; ++np)
#pragma unroll
                for (int rg = 0; rg < 4; ++rg) {
                    const __half2 g = gelu2(c1[2*np][rg], c1[2*np+1][rg]);
                    __half* dst = &h1s[w][mtl*16 + quad*4 + rg][np*32 + col];
                    dst[0]  = __low2half(g);
                    dst[16] = __high2half(g);
                }
        }
        WAVE_LDS_FENCE();

        f32x4 c2s[2][2];
#pragma unroll
        for (int mtl = 0; mtl < 2; ++mtl) {
            const f16x8 a2s0 = *(const f16x8*)&h1s[w][mtl*16 + col][quad * 8];
            const f16x8 a2s1 = *(const f16x8*)&h1s[w][mtl*16 + col][32 + quad * 8];
#pragma unroll
            for (int n = 0; n < 2; ++n) {
                f32x4 c0 = {b2v[n], b2v[n], b2v[n], b2v[n]};
                c0 = __builtin_amdgcn_mfma_f32_16x16x32_f16(a2s0, bw2[0][n], c0, 0, 0, 0);
                c2s[mtl][n] = __builtin_amdgcn_mfma_f32_16x16x32_f16(a2s1, bw2[1][n], c0, 0, 0, 0);
            }
        }
#pragma unroll
        for (int mtl = 0; mtl < 2; ++mtl)
#pragma unroll
            for (int rg = 0; rg < 4; ++rg) {
                const __half2 g = gelu2(c2s[mtl][0][rg], c2s[mtl][1][rg]);
                __half* dst = &h2s[w][mtl*16 + quad*4 + rg][col];
                dst[0]  = __low2half(g);
                dst[16] = __high2half(g);
            }
        WAVE_LDS_FENCE();

#pragma unroll
        for (int mtl = 0; mtl < 2; ++mtl) {
            const int mt = 2 * p + mtl;
            const f16x8 a3 = *(const f16x8*)&h2s[w][mtl*16 + col][quad * 8];
            f32x4 c0 = {b3v, b3v, b3v, b3v};
            const f32x4 c3 = __builtin_amdgcn_mfma_f32_16x16x32_f16(a3, bw3, c0, 0, 0, 0);

#pragma unroll
            for (int rg = 0; rg < 4; ++rg) {
                const int me = e0w + mt * 16 + quad * 4 + rg;
                if (me < E) { vsum += c3[rg]; vsq += c3[rg] * c3[rg]; }
            }
#pragma unroll
            for (int rg = 0; rg < 4; ++rg)
                h1s[w][mtl*16 + quad*4 + rg][col] = __float2half(c3[rg]);
        }

        WAVE_LDS_FENCE();
        {
            const int j    = lane >> 2;
            const int subl = lane & 3;
#pragma unroll
            for (int mtl = 0; mtl < 2; ++mtl) {
                const int mt = 2 * p + mtl;
                const uint2 v = *(const uint2*)&h1s[w][mtl*16 + j][subl * 4];
                const int srcl = (mt << 4) + j;
                const int dR = __shfl(packR, srcl, 64);
                const int dC = __shfl(packC, srcl, 64);
                if (dR >= 0) *(uint2*)((char*)ellA + (size_t)dR * 32 + subl * 8) = v;
                if (dC >= 0) *(uint2*)((char*)ellA + (size_t)dC * 32 + subl * 8) = v;
            }
        }
    }

    vsum += __shfl_xor(vsum, 16, 64);
    vsq  += __shfl_xor(vsq,  16, 64);
    vsum += __shfl_xor(vsum, 32, 64);
    vsq  += __shfl_xor(vsq,  32, 64);
    if (lane < 16) {
        red[w][col]      = vsum;
        red[w][16 + col] = vsq;
    }
    __syncthreads();
    if (t < 32) {
        const float s = red[0][t] + red[1][t] + red[2][t] + red[3][t];
        atomicAdd(&stats[t], s);
    }
}

__global__ __launch_bounds__(WG) void gather_f16(
    const _Float16* __restrict__ ellA, const int* __restrict__ cnt,
    const float* __restrict__ Wp, const float* __restrict__ bp,
    const float* __restrict__ gE, const float* __restrict__ bE,
    float* __restrict__ stats, float* __restrict__ X,
    int N, float invE)
{
    __shared__ float sWp[256];
    __shared__ f32x4 syv[4][16][4];
    __shared__ float red2[4][32];

    const int t = threadIdx.x;
    sWp[t] = Wp[t];

    const int w    = t >> 6;
    const int lane = t & 63;
    const int g    = lane >> 2;
    const int subl = lane & 3;
    const int c0   = subl * 4;

    float a[4], bb[4], bpv[4];
#pragma unroll
    for (int cc = 0; cc < 4; ++cc) {
        const int ch = c0 + cc;
        const float mean = stats[ch] * invE;
        const float var  = stats[16 + ch] * invE - mean * mean;
        a[cc]  = gE[ch] * rsqrtf(var + 1e-5f);
        bb[cc] = bE[ch] - mean * a[cc];
        bpv[cc] = bp[ch];
    }

    const int node = blockIdx.x * 64 + w * 16 + g;

    f32x4 s = {0.f, 0.f, 0.f, 0.f};
    int len = 0;
    if (node < N) {
        len = cnt[node];
        const int cap = len < 64 ? len : 64;
        const char* base = (const char*)ellA + (size_t)node * 2048 + subl * 8;
        int i = 0;
        for (; i + 4 <= cap; i += 4) {
            const uint2 r0 = *(const uint2*)(base + (size_t)(i    ) * 32);
            const uint2 r1 = *(const uint2*)(base + (size_t)(i + 1) * 32);
            const uint2 r2 = *(const uint2*)(base + (size_t)(i + 2) * 32);
            const uint2 r3 = *(const uint2*)(base + (size_t)(i + 3) * 32);
            acc_h4(s, r0); acc_h4(s, r1); acc_h4(s, r2); acc_h4(s, r3);
        }
        for (; i < cap; ++i)
            acc_h4(s, *(const uint2*)(base + (size_t)i * 32));
    }

    const float d    = (float)len;
    const float invd = 1.0f / fmaxf(d, 1.0f);
    f32x4 y;
#pragma unroll
    for (int cc = 0; cc < 4; ++cc)
        y[cc] = (a[cc] * s[cc] + bb[cc] * d) * invd;

    syv[w][g][subl] = y;
    __syncthreads();

    const f32x4 y0 = syv[w][g][0];
    const f32x4 y1 = syv[w][g][1];
    const f32x4 y2 = syv[w][g][2];
    const f32x4 y3 = syv[w][g][3];

    const f32x4* sWp4 = (const f32x4*)sWp;
    f32x4 x = {bpv[0], bpv[1], bpv[2], bpv[3]};
#pragma unroll
    for (int j = 0; j < 4; ++j) {
        const f32x4 wj = sWp4[j * 4 + subl];
#pragma unroll
        for (int cc = 0; cc < 4; ++cc) x[cc] += y0[j] * wj[cc];
    }
#pragma unroll
    for (int j = 0; j < 4; ++j) {
        const f32x4 wj = sWp4[(4 + j) * 4 + subl];
#pragma unroll
        for (int cc = 0; cc < 4; ++cc) x[cc] += y1[j] * wj[cc];
    }
#pragma unroll
    for (int j = 0; j < 4; ++j) {
        const f32x4 wj = sWp4[(8 + j) * 4 + subl];
#pragma unroll
        for (int cc = 0; cc < 4; ++cc) x[cc] += y2[j] * wj[cc];
    }
#pragma unroll
    for (int j = 0; j < 4; ++j) {
        const f32x4 wj = sWp4[(12 + j) * 4 + subl];
#pragma unroll
        for (int cc = 0; cc < 4; ++cc) x[cc] += y3[j] * wj[cc];
    }

    if (node < N) {
        *(f32x4*)&X[(size_t)node * 16 + c0] = x;
    } else {
        x = (f32x4){0.f, 0.f, 0.f, 0.f};
    }

    f32x4 vs = x, vq;
#pragma unroll
    for (int cc = 0; cc < 4; ++cc) vq[cc] = x[cc] * x[cc];
#pragma unroll
    for (int off = 4; off <= 32; off <<= 1) {
#pragma unroll
        for (int cc = 0; cc < 4; ++cc) {
            vs[cc] += __shfl_xor(vs[cc], off, 64);
            vq[cc] += __shfl_xor(vq[cc], off, 64);
        }
    }
    if (lane < 4) {
#pragma unroll
        for (int cc = 0; cc < 4; ++cc) {
            red2[w][c0 + cc]      = vs[cc];
            red2[w][16 + c0 + cc] = vq[cc];
        }
    }
    __syncthreads();
    if (t < 32) {
        const float ssum = red2[0][t] + red2[1][t] + red2[2][t] + red2[3][t];
        atomicAdd(&stats[32 + t], ssum);
    }
}

// ---- apply node BN (in-place, X == out) ----
__global__ __launch_bounds__(WG) void out_kernel(
    const float* __restrict__ X, const float* __restrict__ stats,
    const float* __restrict__ gN, const float* __restrict__ bN,
    float* __restrict__ out, int total, float invN)
{
    __shared__ float sA[16], sB[16];
    if (threadIdx.x < 16) {
        const int k = threadIdx.x;
        const float mean = stats[32 + k] * invN;
        const float var  = stats[48 + k] * invN - mean * mean;
        const float a    = gN[k] / sqrtf(var + 1e-5f);
        sA[k] = a;
        sB[k] = bN[k] - mean * a;
    }
    __syncthreads();
    const int i = blockIdx.x * WG + threadIdx.x;
    if (i < total) {
        out[i] = sA[i & 15] * X[i] + sB[i & 15];
    }
}

// ============================ LAUNCH ============================

extern "C" void kernel_launch(void* const* d_in, const int* in_sizes, int n_in,
                              void* d_out, int out_size, void* d_ws, size_t ws_size,
                              hipStream_t stream)
{
    const float* coords  = (const float*)d_in[0];
    const float* normals = (const float*)d_in[1];
    const float* curv    = (const float*)d_in[2];
    const int*   eidx    = (const int*)d_in[3];
    const float* W1 = (const float*)d_in[4];
    const float* b1 = (const float*)d_in[5];
    const float* W2 = (const float*)d_in[6];
    const float* b2 = (const float*)d_in[7];
    const float* W3 = (const float*)d_in[8];
    const float* b3 = (const float*)d_in[9];
    const float* gE = (const float*)d_in[10];
    const float* bE = (const float*)d_in[11];
    const float* Wp = (const float*)d_in[12];
    const float* bp = (const float*)d_in[13];
    const float* gN = (const float*)d_in[14];
    const float* bN = (const float*)d_in[15];

    const int N = in_sizes[0] / 3;
    const int E = in_sizes[3] / 2;
    const int eblk = (E + WG - 1) / WG;
    float* out = (float*)d_out;

    const size_t off_cnt   = 256;
    const size_t cnt_bytes = (((size_t)N * 4) + 255) & ~(size_t)255;

    // ---------- f32 full-line path: stats | cnt | ellA[N*64 rows x 64B] ~410MB ----------
    // (round 10's 413MB layout demonstrably fit in ws)
    {
        const size_t need = off_cnt + cnt_bytes + (size_t)N * 4096;
        if (ws_size >= need) {
            float* stats = (float*)d_ws;
            int*   cnt   = (int*)((char*)d_ws + off_cnt);
            float* ellA  = (float*)((char*)d_ws + off_cnt + cnt_bytes);

            hipMemsetAsync(d_ws, 0, off_cnt + (size_t)N * 4, stream);

            edge_mlp_f32<<<dim3(eblk), dim3(WG), 0, stream>>>(
                coords, normals, curv, eidx, W1, b1, W2, b2, W3, b3,
                cnt, ellA, stats, E);

            gather_f32<<<dim3((N + 63) / 64), dim3(WG), 0, stream>>>(
                ellA, cnt, Wp, bp, gE, bE, stats, out, N, 1.0f / (float)E);

            out_kernel<<<dim3((N * 16 + WG - 1) / WG), dim3(WG), 0, stream>>>(
                out, stats, gN, bN, out, N * 16, 1.0f / (float)N);
            return;
        }
    }

    // ---------- f16 fallback: stats | cnt | ellA[N*64 rows x 32B] ~206MB ----------
    {
        float*    stats = (float*)d_ws;
        int*      cnt   = (int*)((char*)d_ws + off_cnt);
        _Float16* ellA  = (_Float16*)((char*)d_ws + off_cnt + cnt_bytes);

        hipMemsetAsync(d_ws, 0, off_cnt + (size_t)N * 4, stream);

        edge_mlp_f16<<<dim3(eblk), dim3(WG), 0, stream>>>(
            coords, normals, curv, eidx, W1, b1, W2, b2, W3, b3,
            cnt, ellA, stats, E);

        gather_f16<<<dim3((N + 63) / 64), dim3(WG), 0, stream>>>(
            ellA, cnt, Wp, bp, gE, bE, stats, out, N, 1.0f / (float)E);

        out_kernel<<<dim3((N * 16 + WG - 1) / WG), dim3(WG), 0, stream>>>(
            out, stats, gN, bN, out, N * 16, 1.0f / (float)N);
    }
}